// Round 1
// baseline (5019.812 us; speedup 1.0000x reference)
//
#include <hip/hip_runtime.h>
#include <hip/hip_fp16.h>

typedef unsigned int u32;
typedef _Float16 half2_t __attribute__((ext_vector_type(2)));

static constexpr int PL = 300;
static constexpr int QL = 50;
static constexpr int B  = 32;
static constexpr int D  = 256;
static constexpr int H  = 256;

__device__ __forceinline__ float fdot2(u32 w, u32 x, float acc) {
    return __builtin_amdgcn_fdot2(__builtin_bit_cast(half2_t, w),
                                  __builtin_bit_cast(half2_t, x), acc, false);
}

// ---------------- pack Wr [2][256][256] f32 -> chunk8-packed f16 ----------------
// dst uint index: ((g*32 + kc)*256 + j)*4 + w  ; covers source cols k = kc*8+2w, +1
__global__ __launch_bounds__(256) void pack256(const float* __restrict__ W,
                                               u32* __restrict__ dst) {
    int id = blockIdx.x * 256 + threadIdx.x;      // < 65536
    int g  = id >> 15;
    int r  = id & 32767;
    int kc = r >> 10;
    int j  = (r >> 2) & 255;
    int w  = r & 3;
    int k  = kc * 8 + w * 2;
    const float* s = &W[(g * 256 + j) * 256 + k];
    half2_t h2; h2[0] = (_Float16)s[0]; h2[1] = (_Float16)s[1];
    dst[id] = __builtin_bit_cast(u32, h2);
}

// ---------------- pack Wc = [W_ih | W_hh] rows of K=768 ----------------
// dst uint index: ((g*96 + kc)*1024 + j)*4 + w
__global__ __launch_bounds__(256) void packWc(const float* __restrict__ Wih,
                                              const float* __restrict__ Whh,
                                              u32* __restrict__ dst) {
    int id = blockIdx.x * 256 + threadIdx.x;      // < 786432
    int g  = id / 393216;
    int r  = id % 393216;
    int kc = r >> 12;
    int j  = (r >> 2) & 1023;
    int w  = r & 3;
    int k  = kc * 8 + w * 2;
    float a, bb;
    if (k < 512) { const float* s = &Wih[(g * 1024 + j) * 512 + k];         a = s[0]; bb = s[1]; }
    else         { const float* s = &Whh[(g * 1024 + j) * 256 + (k - 512)]; a = s[0]; bb = s[1]; }
    half2_t h2; h2[0] = (_Float16)a; h2[1] = (_Float16)bb;
    dst[id] = __builtin_bit_cast(u32, h2);
}

// ---------------- prep: out[g][b][t][h] = bias[g][h] + sum_d X[t][b][d]*W[g][h][d] ----------------
__global__ __launch_bounds__(256) void prep_proj(const float* __restrict__ X,
                                                 const float* __restrict__ W,
                                                 const float* __restrict__ Bv,
                                                 __half* __restrict__ out,
                                                 int T, int nt) {
    int id = blockIdx.x;
    int tb = id % nt; id /= nt;
    int b  = id % B;  id /= B;
    int g  = id;
    int t0 = tb * 8;
    int nr = T - t0; if (nr > 8) nr = 8;
    __shared__ __align__(16) float xs[8][256];
    int tid = threadIdx.x;
    for (int r = 0; r < nr; r++) xs[r][tid] = X[((t0 + r) * B + b) * D + tid];
    __syncthreads();
    const float4* wrow = (const float4*)&W[(g * H + tid) * D];
    float bb = Bv[g * H + tid];
    float acc[8];
#pragma unroll
    for (int r = 0; r < 8; r++) acc[r] = bb;
    for (int d4 = 0; d4 < D / 4; d4++) {
        float4 w = wrow[d4];
#pragma unroll
        for (int r = 0; r < 8; r++) {
            float4 x = *(const float4*)&xs[r][d4 * 4];
            acc[r] = fmaf(w.x, x.x, fmaf(w.y, x.y, fmaf(w.z, x.z, fmaf(w.w, x.w, acc[r]))));
        }
    }
    for (int r = 0; r < nr; r++)
        out[((g * B + b) * T + t0 + r) * H + tid] = __float2half(acc[r]);
}

// ---------------- main scan: one block per (dir, batch) ----------------
__global__ __launch_bounds__(512) void scan_k(
    const float* __restrict__ cv,      // [300][32][256]
    const int*   __restrict__ cmask,   // [32][300]
    const float* __restrict__ qv,      // [50][32][256]
    const int*   __restrict__ qmask,   // [32][50]
    const float* __restrict__ Wgv,     // [2][256]
    const float* __restrict__ bgv,     // [2]
    const float* __restrict__ lngp,    // [2][512]
    const float* __restrict__ lnbp,    // [2][512]
    const float* __restrict__ brp,     // [2][256]
    const float* __restrict__ bih,     // [2][1024]
    const float* __restrict__ bhh,     // [2][1024]
    const u32*   __restrict__ Wr4,     // packed
    const u32*   __restrict__ Wc4,     // packed
    const __half* __restrict__ whp,    // [2][32][50][256]
    const __half* __restrict__ hpp,    // [2][32][300][256]
    float* __restrict__ out)           // [300][32][512]
{
    int wg = blockIdx.x;               // 0..63
    int g = wg >> 5, b = wg & 31;
    int tid  = threadIdx.x;
    int lane = tid & 63, wave = tid >> 6;

    __shared__ __align__(16) u32  sh_whu[6400];   // wh as half[50][256]
    __shared__ __align__(16) u32  sh_qvu[6400];   // qv as half[50][256]
    __shared__ __align__(16) u32  sh_x[384];      // x = [z f16x512 | h f16x256] as half2 words
    __shared__ __align__(16) float sh_zf[512];
    __shared__ float sh_g[1024];
    __shared__ float sh_h[256];
    __shared__ float sh_c[256];
    __shared__ float sh_hrA[256];
    __shared__ float sh_hrB[256];
    __shared__ float sh_alpha[64];
    __shared__ float sh_red[20];
    __shared__ int   sh_len;

    // ---- prologue: stage wh, qv(f16); zero state; length; zero output tail ----
    const u32* whsrc = (const u32*)(whp + (size_t)(g * B + b) * QL * H);
    for (int i = tid; i < 6400; i += 512) sh_whu[i] = whsrc[i];
    for (int i = tid; i < 6400; i += 512) {
        int q = i >> 7, d2 = i & 127;
        float2 v = *(const float2*)&qv[(q * B + b) * D + d2 * 2];
        half2_t h2; h2[0] = (_Float16)v.x; h2[1] = (_Float16)v.y;
        sh_qvu[i] = __builtin_bit_cast(u32, h2);
    }
    if (tid < 256) { sh_h[tid] = 0.f; sh_c[tid] = 0.f; }
    if (wave == 0) {
        int s = 0;
        for (int t = lane; t < PL; t += 64) s += cmask[b * PL + t];
#pragma unroll
        for (int m = 32; m; m >>= 1) s += __shfl_xor(s, m, 64);
        if (lane == 0) sh_len = s;
    }
    __syncthreads();
    int len = sh_len;
    for (int i = tid; i < (PL - len) * 256; i += 512) {
        int t = len + (i >> 8), ch = i & 255;
        out[(t * B + b) * 512 + g * 256 + ch] = 0.f;
    }

    // ---- hoisted per-thread constants ----
    float wgr[4];
#pragma unroll
    for (int i = 0; i < 4; i++) wgr[i] = Wgv[g * H + lane + i * 64];
    float bgs = bgv[g];
    float bias1 = bih[g * 1024 + tid]       + bhh[g * 1024 + tid];
    float bias2 = bih[g * 1024 + 512 + tid] + bhh[g * 1024 + 512 + tid];
    float2 lng = {0.f, 0.f}, lnb = {0.f, 0.f};
    float brv = 0.f;
    if (tid < 256) {
        lng = *(const float2*)&lngp[g * 512 + 2 * tid];
        lnb = *(const float2*)&lnbp[g * 512 + 2 * tid];
        brv = brp[g * H + tid];
    }
    const uint4* wrq = (const uint4*)Wr4 + (size_t)g * 8192;
    const uint4* wcq = (const uint4*)Wc4 + (size_t)g * (96 * 1024);
    const __half* hpb = hpp + (size_t)(g * B + b) * PL * H;

    // ---- sequential scan ----
    for (int t = 0; t < len; t++) {
        int t_src = g ? (len - 1 - t) : t;

        // P0: cv row -> zf[0:256]; pack h -> sh_x[256:384)
        if (tid < 256) {
            sh_zf[tid] = cv[(t_src * B + b) * D + tid];
        } else if (tid >= 384) {
            int i = tid - 384;
            half2_t h2; h2[0] = (_Float16)sh_h[2 * i]; h2[1] = (_Float16)sh_h[2 * i + 1];
            sh_x[256 + i] = __builtin_bit_cast(u32, h2);
        }
        __syncthreads();

        // P1: hr gemv (dot over h), split 2-way across thread halves
        {
            int s = tid >> 8, h = tid & 255;
            float acc = s ? 0.f : brv;
            const uint4* wr = wrq + h;
#pragma unroll 4
            for (int kc = s * 16; kc < s * 16 + 16; kc++) {
                uint4 xw = *(const uint4*)&sh_x[256 + kc * 4];
                uint4 ww = wr[kc * 256];
                acc = fdot2(ww.x, xw.x, acc);
                acc = fdot2(ww.y, xw.y, acc);
                acc = fdot2(ww.z, xw.z, acc);
                acc = fdot2(ww.w, xw.w, acc);
            }
            (s ? sh_hrB : sh_hrA)[h] = acc;
        }
        __syncthreads();

        // P2: attention logits per q (wave-parallel over q, lane covers 4 h)
        {
            const __half* hp_row = hpb + (size_t)t_src * H;
            float rp[4];
#pragma unroll
            for (int i = 0; i < 4; i++) {
                int h = lane + i * 64;
                rp[i] = sh_hrA[h] + sh_hrB[h] + (float)hp_row[h];
            }
            const __half* whh = (const __half*)sh_whu;
            for (int q = wave; q < QL; q += 8) {
                float a = 0.f;
#pragma unroll
                for (int i = 0; i < 4; i++) {
                    int h = lane + i * 64;
                    float x = (float)whh[q * H + h] + rp[i];
                    float e = __expf(2.f * x);
                    float th = (e - 1.f) / (e + 1.f);
                    a = fmaf(wgr[i], th, a);
                }
#pragma unroll
                for (int m = 32; m; m >>= 1) a += __shfl_xor(a, m, 64);
                if (lane == 0)
                    sh_alpha[q] = (qmask[b * QL + q] == 0) ? -1e30f : (a + bgs);
            }
        }
        __syncthreads();

        // P3: masked softmax over 50 q (wave 0)
        if (wave == 0) {
            float v = (lane < QL) ? sh_alpha[lane] : -1e30f;
            float m = v;
#pragma unroll
            for (int s = 32; s; s >>= 1) m = fmaxf(m, __shfl_xor(m, s, 64));
            float e = (lane < QL) ? __expf(v - m) : 0.f;
            float sum = e;
#pragma unroll
            for (int s = 32; s; s >>= 1) sum += __shfl_xor(sum, s, 64);
            if (lane < QL) sh_alpha[lane] = e / sum;
        }
        __syncthreads();

        // P4: h_alpha -> zf[256:512)
        if (tid < 256) {
            const __half* qvh = (const __half*)sh_qvu;
            float s = 0.f;
            for (int q = 0; q < QL; q++)
                s = fmaf(sh_alpha[q], (float)qvh[q * H + tid], s);
            sh_zf[256 + tid] = s;
        }
        __syncthreads();

        // P5: layernorm over 512, pack normalized z (f16) -> sh_x[0:256)
        {
            float v = sh_zf[tid];
            float sx = v, sxx = v * v;
#pragma unroll
            for (int s = 32; s; s >>= 1) { sx += __shfl_xor(sx, s, 64); sxx += __shfl_xor(sxx, s, 64); }
            if (lane == 0) { sh_red[wave * 2] = sx; sh_red[wave * 2 + 1] = sxx; }
        }
        __syncthreads();
        if (tid == 0) {
            float s = 0.f, ss = 0.f;
#pragma unroll
            for (int w = 0; w < 8; w++) { s += sh_red[2 * w]; ss += sh_red[2 * w + 1]; }
            float mu = s * (1.f / 512.f);
            float var = ss * (1.f / 512.f) - mu * mu;
            sh_red[16] = mu; sh_red[17] = rsqrtf(var + 1e-5f);
        }
        __syncthreads();
        if (tid < 256) {
            float mu = sh_red[16], rs = sh_red[17];
            float2 z = *(const float2*)&sh_zf[2 * tid];
            float z0 = (z.x - mu) * rs * lng.x + lnb.x;
            float z1 = (z.y - mu) * rs * lng.y + lnb.y;
            half2_t h2; h2[0] = (_Float16)z0; h2[1] = (_Float16)z1;
            sh_x[tid] = __builtin_bit_cast(u32, h2);
        }
        __syncthreads();

        // P6: gates = x @ Wc^T  (each thread: outputs tid and tid+512)
        {
            float a1 = bias1, a2 = bias2;
#pragma unroll 2
            for (int kc = 0; kc < 96; kc++) {
                uint4 xw = *(const uint4*)&sh_x[kc * 4];
                uint4 w1 = wcq[kc * 1024 + tid];
                uint4 w2 = wcq[kc * 1024 + 512 + tid];
                a1 = fdot2(w1.x, xw.x, a1); a1 = fdot2(w1.y, xw.y, a1);
                a1 = fdot2(w1.z, xw.z, a1); a1 = fdot2(w1.w, xw.w, a1);
                a2 = fdot2(w2.x, xw.x, a2); a2 = fdot2(w2.y, xw.y, a2);
                a2 = fdot2(w2.z, xw.z, a2); a2 = fdot2(w2.w, xw.w, a2);
            }
            sh_g[tid] = a1; sh_g[512 + tid] = a2;
        }
        __syncthreads();

        // P7: LSTM pointwise + output store
        if (tid < 256) {
            float iv = sh_g[tid], fv = sh_g[256 + tid], gv = sh_g[512 + tid], ov = sh_g[768 + tid];
            float si = 1.f / (1.f + __expf(-iv));
            float sf = 1.f / (1.f + __expf(-fv));
            float so = 1.f / (1.f + __expf(-ov));
            float eg = __expf(2.f * gv); float tg = (eg - 1.f) / (eg + 1.f);
            float c = sf * sh_c[tid] + si * tg;
            float ec = __expf(2.f * c); float tc = (ec - 1.f) / (ec + 1.f);
            float hv = so * tc;
            sh_c[tid] = c; sh_h[tid] = hv;
            out[(t_src * B + b) * 512 + g * 256 + tid] = hv;
        }
        __syncthreads();
    }
}

extern "C" void kernel_launch(void* const* d_in, const int* in_sizes, int n_in,
                              void* d_out, int out_size, void* d_ws, size_t ws_size,
                              hipStream_t stream) {
    const float* cv    = (const float*)d_in[0];
    const int*   cmask = (const int*)  d_in[1];
    const float* qv    = (const float*)d_in[2];
    const int*   qmask = (const int*)  d_in[3];
    const float* Wq    = (const float*)d_in[4];
    const float* bq    = (const float*)d_in[5];
    const float* Wp    = (const float*)d_in[6];
    const float* bp    = (const float*)d_in[7];
    const float* Wr    = (const float*)d_in[8];
    const float* br    = (const float*)d_in[9];
    const float* Wg    = (const float*)d_in[10];
    const float* bg    = (const float*)d_in[11];
    const float* ln_g  = (const float*)d_in[12];
    const float* ln_b  = (const float*)d_in[13];
    const float* Wih   = (const float*)d_in[14];
    const float* Whh   = (const float*)d_in[15];
    const float* b_ih  = (const float*)d_in[16];
    const float* b_hh  = (const float*)d_in[17];
    float* out = (float*)d_out;

    uint8_t* ws = (uint8_t*)d_ws;
    u32*    Wr4 = (u32*)ws;    ws += (size_t)2 * 32 * 256 * 4 * 4;    // 256 KB
    u32*    Wc4 = (u32*)ws;    ws += (size_t)2 * 96 * 1024 * 4 * 4;   // 3 MB
    __half* whp = (__half*)ws; ws += (size_t)2 * 32 * 50 * 256 * 2;   // 1.6 MB
    __half* hpp = (__half*)ws;                                        // 9.8 MB

    hipLaunchKernelGGL(pack256, dim3(256), dim3(256), 0, stream, Wr, Wr4);
    hipLaunchKernelGGL(packWc, dim3(3072), dim3(256), 0, stream, Wih, Whh, Wc4);
    hipLaunchKernelGGL(prep_proj, dim3(2 * 32 * 7), dim3(256), 0, stream,
                       qv, Wq, bq, whp, QL, 7);
    hipLaunchKernelGGL(prep_proj, dim3(2 * 32 * 38), dim3(256), 0, stream,
                       cv, Wp, bp, hpp, PL, 38);
    hipLaunchKernelGGL(scan_k, dim3(64), dim3(512), 0, stream,
                       cv, cmask, qv, qmask, Wg, bg, ln_g, ln_b, br, b_ih, b_hh,
                       Wr4, Wc4, whp, hpp, out);
}